// Round 7
// baseline (285.837 us; speedup 1.0000x reference)
//
#include <hip/hip_runtime.h>

// ---------- helpers ----------
typedef __attribute__((ext_vector_type(8))) __bf16 bf16x8;
typedef __attribute__((ext_vector_type(8))) unsigned short u16x8;
typedef __attribute__((ext_vector_type(16))) float f32x16;

__device__ inline unsigned short f2bf(float f) {
    union { float f; unsigned int i; } v; v.f = f;
    unsigned int i = v.i;
    unsigned int r = i + 0x7FFFu + ((i >> 16) & 1u);   // RNE
    return (unsigned short)(r >> 16);
}
__device__ inline float bf2f(unsigned short u) {
    union { unsigned int i; float f; } v; v.i = ((unsigned int)u) << 16; return v.f;
}

__device__ inline void gload_lds16(const void* g, void* l) {
    __builtin_amdgcn_global_load_lds(
        (const __attribute__((address_space(1))) unsigned int*)g,
        (__attribute__((address_space(3))) unsigned int*)l, 16, 0, 0);
}

// inline-asm LDS read (32-bit byte offset, dynamic-LDS base 0); invisible to
// the memory legalizer -> no compiler vmcnt/lgkm drains against our pipeline.
__device__ inline bf16x8 ldsrd(unsigned off) {
    bf16x8 r;
    asm volatile("ds_read_b128 %0, %1" : "=v"(r) : "v"(off));
    return r;
}

// ---------- kernel 1: cast x (fp32 -> bf16) ----------
__global__ __launch_bounds__(256) void cast_x(const float* __restrict__ x,
                                              unsigned short* __restrict__ xb, int n4) {
    int idx = blockIdx.x * blockDim.x + threadIdx.x;
    int stride = gridDim.x * blockDim.x;
    for (int i = idx; i < n4; i += stride) {
        float4 v = ((const float4*)x)[i];
        ushort4 o;
        o.x = f2bf(v.x); o.y = f2bf(v.y); o.z = f2bf(v.z); o.w = f2bf(v.w);
        ((ushort4*)xb)[i] = o;
    }
}

// ---------- kernel 2: cast W into Wcat rows 0..1023 ----------
__global__ __launch_bounds__(256) void cast_w(const float* __restrict__ W,
                                              unsigned short* __restrict__ wcat) {
    int i = blockIdx.x * 256 + threadIdx.x;
    float4 v = ((const float4*)W)[i];
    ushort4 o;
    o.x = f2bf(v.x); o.y = f2bf(v.y); o.z = f2bf(v.z); o.w = f2bf(v.w);
    ((ushort4*)wcat)[i] = o;
}

// ---------- kernel 3: build M^T into Wcat rows 1024..2047 ----------
__global__ __launch_bounds__(256) void build_m(const float* __restrict__ A,
                                               const float* __restrict__ Bm,
                                               const float* __restrict__ scores,
                                               unsigned short* __restrict__ wcat) {
    int D = blockIdx.x;      // 1024
    int tx = threadIdx.x;    // 256
    float acc[4] = {0.f, 0.f, 0.f, 0.f};
    for (int e = 0; e < 16; ++e) {
        float pe = scores[e];
        float bb[16];
        #pragma unroll
        for (int r = 0; r < 16; ++r) bb[r] = pe * Bm[(size_t)((e << 4) + r) * 1024 + D];
        #pragma unroll
        for (int j = 0; j < 4; ++j) {
            int d = tx + j * 256;
            const float4* ap = (const float4*)(A + (((size_t)e * 1024 + d) << 4));
            float4 a0 = ap[0], a1 = ap[1], a2 = ap[2], a3 = ap[3];
            acc[j] += a0.x*bb[0]  + a0.y*bb[1]  + a0.z*bb[2]  + a0.w*bb[3]
                    + a1.x*bb[4]  + a1.y*bb[5]  + a1.z*bb[6]  + a1.w*bb[7]
                    + a2.x*bb[8]  + a2.y*bb[9]  + a2.z*bb[10] + a2.w*bb[11]
                    + a3.x*bb[12] + a3.y*bb[13] + a3.z*bb[14] + a3.w*bb[15];
        }
    }
    size_t rowbase = (size_t)(1024 + D) * 1024;
    #pragma unroll
    for (int j = 0; j < 4; ++j) wcat[rowbase + tx + j * 256] = f2bf(acc[j]);
}

// ---------- kernel 4: 256x256-tile GEMM, 32x32x16 MFMA, 1 barrier/K-tile ----------
// out2[t][n] = sum_k xb[t][k] * wcat[n][k];  M=32768, N=2048, K=1024.
// BM=BN=256, BK=64, 8 waves (2Mx4N, wave tile 128x64), 128KiB LDS dbuf.
// LDS per buf (64KB): A [256 rows][64 k] @0, B same @32768; 128B rows,
// 16B-chunk XOR swizzle (chunk_phys = chunk ^ (row&7)) applied on the global
// staging source AND the ds_read offsets (involution, rule 21).
// Schedule: all stages -> other buf (no intra-tile WAR) => ONE barrier per
// K-tile; ks-pipelined ds_reads with counted lgkmcnt(6); vmcnt(0) at tile end.
__global__ __launch_bounds__(512, 2) void gemm_zm32(const unsigned short* __restrict__ xb,
                                                    const unsigned short* __restrict__ wcat,
                                                    const float* __restrict__ bias,
                                                    float* __restrict__ zout) {
    extern __shared__ char lds[];
    const int tid = threadIdx.x;
    const int l = tid & 63;
    const int w = tid >> 6;
    const int wr = w >> 2;        // 0..1  (M half: rows wr*128 + [0,128))
    const int wc = w & 3;         // 0..3  (N quarter: cols wc*64 + [0,64))

    const int bid = blockIdx.x;
    const int swz = (bid & 7) * 128 + (bid >> 3);
    const int brow = (swz >> 3) * 256;    // 128 M-tiles
    const int bcol = (swz & 7) * 256;     // 8 N-tiles

    // 32x32x16 A/B fragment: lane holds row (l&31), k in (l>>5)*8 + [0,8)
    const unsigned rA = (unsigned)((wr * 128 + (l & 31)) * 128);
    const unsigned rB = 32768u + (unsigned)((wc * 64 + (l & 31)) * 128);
    const unsigned kx = (unsigned)(l & 7);
    const unsigned hk = (unsigned)(l >> 5);
    const unsigned ck0 = ((0u + hk) ^ kx) * 16u;   // ks0: k 0..15
    const unsigned ck1 = ((2u + hk) ^ kx) * 16u;   // ks1: k 16..31
    const unsigned ck2 = ((4u + hk) ^ kx) * 16u;   // ks2: k 32..47
    const unsigned ck3 = ((6u + hk) ^ kx) * 16u;   // ks3: k 48..63

    // staging: thread ti covers row h*128 + ti/8 (+64), phys chunk ti%8,
    // source logical chunk = (ti%8) ^ (row&7)
    const unsigned strow = (unsigned)(tid >> 3);
    const unsigned stchunk = (unsigned)((tid & 7) ^ (strow & 7));
    const unsigned stlds = (unsigned)(tid * 16);

    f32x16 acc[4][2] = {};

#define STAGE(mat, baserow, T, h, bofs, dst) do {                                   \
        int T_ = (T); int Ts_ = T_ > 15 ? 15 : T_;                                  \
        unsigned db_ = (dst) + (bofs) + (h) * 16384u;                               \
        const unsigned short* g_ = (mat) + (size_t)((baserow) + (h) * 128 + strow) * 1024 \
                                   + Ts_ * 64 + stchunk * 8;                        \
        gload_lds16(g_,           lds + db_ + stlds);                               \
        gload_lds16(g_ + 64*1024, lds + db_ + 8192 + stlds);                        \
    } while (0)

#define RDK(AF, BF, bufo, CK) do {                                                  \
        AF[0] = ldsrd((bufo) + rA +     0 + (CK));                                  \
        AF[1] = ldsrd((bufo) + rA +  4096 + (CK));                                  \
        AF[2] = ldsrd((bufo) + rA +  8192 + (CK));                                  \
        AF[3] = ldsrd((bufo) + rA + 12288 + (CK));                                  \
        BF[0] = ldsrd((bufo) + rB +     0 + (CK));                                  \
        BF[1] = ldsrd((bufo) + rB +  4096 + (CK));                                  \
    } while (0)

#define LGKM6_SB() do {                                                             \
        asm volatile("s_waitcnt lgkmcnt(6)" ::: "memory");                          \
        __builtin_amdgcn_sched_barrier(0);                                          \
    } while (0)
#define LGKM0_SB() do {                                                             \
        asm volatile("s_waitcnt lgkmcnt(0)" ::: "memory");                          \
        __builtin_amdgcn_sched_barrier(0);                                          \
    } while (0)

#define MFMA8(AF, BF) do {                                                          \
        __builtin_amdgcn_s_setprio(1);                                              \
        acc[0][0] = __builtin_amdgcn_mfma_f32_32x32x16_bf16(AF[0], BF[0], acc[0][0], 0, 0, 0); \
        acc[1][0] = __builtin_amdgcn_mfma_f32_32x32x16_bf16(AF[1], BF[0], acc[1][0], 0, 0, 0); \
        acc[2][0] = __builtin_amdgcn_mfma_f32_32x32x16_bf16(AF[2], BF[0], acc[2][0], 0, 0, 0); \
        acc[3][0] = __builtin_amdgcn_mfma_f32_32x32x16_bf16(AF[3], BF[0], acc[3][0], 0, 0, 0); \
        acc[0][1] = __builtin_amdgcn_mfma_f32_32x32x16_bf16(AF[0], BF[1], acc[0][1], 0, 0, 0); \
        acc[1][1] = __builtin_amdgcn_mfma_f32_32x32x16_bf16(AF[1], BF[1], acc[1][1], 0, 0, 0); \
        acc[2][1] = __builtin_amdgcn_mfma_f32_32x32x16_bf16(AF[2], BF[1], acc[2][1], 0, 0, 0); \
        acc[3][1] = __builtin_amdgcn_mfma_f32_32x32x16_bf16(AF[3], BF[1], acc[3][1], 0, 0, 0); \
        __builtin_amdgcn_s_setprio(0);                                              \
    } while (0)

    // ---- prologue: tile 0 -> buf0 (8 gload_lds) ----
    STAGE(xb,   brow, 0, 0, 0u,      0u);
    STAGE(wcat, bcol, 0, 0, 32768u,  0u);
    STAGE(xb,   brow, 0, 1, 0u,      0u);
    STAGE(wcat, bcol, 0, 1, 32768u,  0u);
    asm volatile("s_waitcnt vmcnt(0)" ::: "memory");
    __builtin_amdgcn_s_barrier();

    bf16x8 a0[4], b0[2], a1[4], b1[2];
    for (int t = 0; t < 16; ++t) {
        const unsigned bufo = (unsigned)((t & 1) * 65536);
        const unsigned nbuf = bufo ^ 65536u;

        RDK(a0, b0, bufo, ck0);                     // ks0 reads
        STAGE(xb, brow, t + 1, 0, 0u, nbuf);        // A-h0(t+1)
        RDK(a1, b1, bufo, ck1);                     // ks1 reads (in flight)
        LGKM6_SB();                                 // ks0 landed
        MFMA8(a0, b0);

        STAGE(wcat, bcol, t + 1, 0, 32768u, nbuf);  // B-h0(t+1)
        RDK(a0, b0, bufo, ck2);                     // ks2 reads
        LGKM6_SB();                                 // ks1 landed
        MFMA8(a1, b1);

        STAGE(xb, brow, t + 1, 1, 0u, nbuf);        // A-h1(t+1)
        RDK(a1, b1, bufo, ck3);                     // ks3 reads
        LGKM6_SB();                                 // ks2 landed
        MFMA8(a0, b0);

        STAGE(wcat, bcol, t + 1, 1, 32768u, nbuf);  // B-h1(t+1)
        LGKM0_SB();                                 // ks3 landed
        MFMA8(a1, b1);

        // all 8 stage-loads for t+1 were issued >=1 phase ago; drain + sync
        asm volatile("s_waitcnt vmcnt(0)" ::: "memory");
        __builtin_amdgcn_s_barrier();
    }

    // ---- C-write: scatter acc -> LDS [256][256] bf16, then coalesced out ----
    // 32x32 C/D layout: col = l&31, row = (reg&3) + 8*(reg>>2) + 4*(l>>5)
    unsigned short* tlds = (unsigned short*)lds;
    const bool is_z = (bcol < 1024);
    {
        const int colloc0 = wc * 64 + (l & 31);
        const int rowloc0 = wr * 128 + 4 * (l >> 5);
        #pragma unroll
        for (int fn = 0; fn < 2; ++fn) {
            int colloc = colloc0 + fn * 32;
            float bb = is_z ? bias[bcol + colloc] : 0.f;
            #pragma unroll
            for (int fm = 0; fm < 4; ++fm) {
                #pragma unroll
                for (int reg = 0; reg < 16; ++reg) {
                    int row = rowloc0 + fm * 32 + (reg & 3) + 8 * (reg >> 2);
                    tlds[row * 256 + colloc] = f2bf(acc[fm][fn][reg] + bb);
                }
            }
        }
    }
    __syncthreads();
    {
        // d_out as packed bf16: row r = [1024 z | 1024 m] (u16 units, 2048/row)
        unsigned short* og = (unsigned short*)zout;
        const int rr = tid >> 5;           // 0..15
        const int c16 = (tid & 31) * 8;    // u16 col within 256
        #pragma unroll
        for (int p = 0; p < 16; ++p) {
            int row = p * 16 + rr;
            u16x8 v = *(const u16x8*)&tlds[row * 256 + c16];
            *(u16x8*)&og[(size_t)(brow + row) * 2048 + bcol + c16] = v;
        }
    }
#undef STAGE
#undef RDK
#undef LGKM6_SB
#undef LGKM0_SB
#undef MFMA8
}

// ---------- kernel 5: in-place norm-clamp epilogue ----------
// d_out row r arrives as packed bf16 [1024 z | 1024 m]; leaves as 1024 fp32.
__global__ __launch_bounds__(256) void epilogue_ip(float* out, const int* __restrict__ lidx) {
    int row = blockIdx.x;            // 32768
    int tx = threadIdx.x;            // 256
    const unsigned short* io = (const unsigned short*)out;
    size_t base = (size_t)row * 2048;

    ushort4 zv = *(const ushort4*)&io[base + tx * 4];
    ushort4 mv = *(const ushort4*)&io[base + 1024 + tx * 4];
    float z0 = bf2f(zv.x), z1 = bf2f(zv.y), z2 = bf2f(zv.z), z3 = bf2f(zv.w);
    float m0 = bf2f(mv.x), m1 = bf2f(mv.y), m2 = bf2f(mv.z), m3 = bf2f(mv.w);

    float sz = z0 * z0 + z1 * z1 + z2 * z2 + z3 * z3;
    float sm = m0 * m0 + m1 * m1 + m2 * m2 + m3 * m3;

    #pragma unroll
    for (int off = 32; off > 0; off >>= 1) {
        sz += __shfl_xor(sz, off);
        sm += __shfl_xor(sm, off);
    }
    __shared__ float red[8];
    int wv = tx >> 6;
    if ((tx & 63) == 0) { red[wv * 2] = sz; red[wv * 2 + 1] = sm; }
    __syncthreads();   // also orders: ALL row reads complete before ANY writes
    sz = red[0] + red[2] + red[4] + red[6];
    sm = red[1] + red[3] + red[5] + red[7];

    float gamma = fminf(0.5f * sqrtf(sz) / (sqrtf(sm) + 1e-6f), 1.0f);
    if (lidx[0] < 0) gamma = 0.f;

    float4 o;
    o.x = z0 + gamma * m0; o.y = z1 + gamma * m1;
    o.z = z2 + gamma * m2; o.w = z3 + gamma * m3;
    *(float4*)&out[(size_t)row * 1024 + tx * 4] = o;
}

// ---------- launcher ----------
extern "C" void kernel_launch(void* const* d_in, const int* in_sizes, int n_in,
                              void* d_out, int out_size, void* d_ws, size_t ws_size,
                              hipStream_t stream) {
    const float* x  = (const float*)d_in[0];
    const float* W  = (const float*)d_in[1];
    const float* b  = (const float*)d_in[2];
    const float* A  = (const float*)d_in[3];
    const float* Bm = (const float*)d_in[4];
    const float* sc = (const float*)d_in[5];
    const int* lidx = (const int*)d_in[6];
    float* out = (float*)d_out;

    // ws layout (bytes): xb 64MB | wcat 4MB   (68MB total)
    unsigned short* xb   = (unsigned short*)d_ws;
    unsigned short* wcat = (unsigned short*)((char*)d_ws + 67108864);

    hipFuncSetAttribute((const void*)gemm_zm32,
                        hipFuncAttributeMaxDynamicSharedMemorySize, 131072);

    cast_x<<<2048, 256, 0, stream>>>(x, xb, 33554432 / 4);
    cast_w<<<1024, 256, 0, stream>>>(W, wcat);
    build_m<<<1024, 256, 0, stream>>>(A, Bm, sc, wcat);
    gemm_zm32<<<1024, 512, 131072, stream>>>(xb, wcat, b, out);
    epilogue_ip<<<32768, 256, 0, stream>>>(out, lidx);
}

// Round 8
// 276.348 us; speedup vs baseline: 1.0343x; 1.0343x over previous
//
#include <hip/hip_runtime.h>

// ---------- helpers ----------
typedef __attribute__((ext_vector_type(8))) __bf16 bf16x8;
typedef __attribute__((ext_vector_type(8))) unsigned short u16x8;
typedef __attribute__((ext_vector_type(4))) float f32x4;

__device__ inline unsigned short f2bf(float f) {
    union { float f; unsigned int i; } v; v.f = f;
    unsigned int i = v.i;
    unsigned int r = i + 0x7FFFu + ((i >> 16) & 1u);   // RNE
    return (unsigned short)(r >> 16);
}
__device__ inline float bf2f(unsigned short u) {
    union { unsigned int i; float f; } v; v.i = ((unsigned int)u) << 16; return v.f;
}

__device__ inline void gload_lds16(const void* g, void* l) {
    __builtin_amdgcn_global_load_lds(
        (const __attribute__((address_space(1))) unsigned int*)g,
        (__attribute__((address_space(3))) unsigned int*)l, 16, 0, 0);
}

// inline-asm LDS read (32-bit byte offset, dynamic-LDS base 0); invisible to
// the memory legalizer -> no compiler vmcnt/lgkm drains against our pipeline.
__device__ inline bf16x8 ldsrd(unsigned off) {
    bf16x8 r;
    asm volatile("ds_read_b128 %0, %1" : "=v"(r) : "v"(off));
    return r;
}

// ---------- kernel 1: cast x (fp32 -> bf16) ----------
__global__ __launch_bounds__(256) void cast_x(const float* __restrict__ x,
                                              unsigned short* __restrict__ xb, int n4) {
    int idx = blockIdx.x * blockDim.x + threadIdx.x;
    int stride = gridDim.x * blockDim.x;
    for (int i = idx; i < n4; i += stride) {
        float4 v = ((const float4*)x)[i];
        ushort4 o;
        o.x = f2bf(v.x); o.y = f2bf(v.y); o.z = f2bf(v.z); o.w = f2bf(v.w);
        ((ushort4*)xb)[i] = o;
    }
}

// ---------- kernel 2: cast W into Wcat rows 0..1023 ----------
__global__ __launch_bounds__(256) void cast_w(const float* __restrict__ W,
                                              unsigned short* __restrict__ wcat) {
    int i = blockIdx.x * 256 + threadIdx.x;
    float4 v = ((const float4*)W)[i];
    ushort4 o;
    o.x = f2bf(v.x); o.y = f2bf(v.y); o.z = f2bf(v.z); o.w = f2bf(v.w);
    ((ushort4*)wcat)[i] = o;
}

// ---------- kernel 3: build M^T into Wcat rows 1024..2047 ----------
__global__ __launch_bounds__(256) void build_m(const float* __restrict__ A,
                                               const float* __restrict__ Bm,
                                               const float* __restrict__ scores,
                                               unsigned short* __restrict__ wcat) {
    int D = blockIdx.x;      // 1024
    int tx = threadIdx.x;    // 256
    float acc[4] = {0.f, 0.f, 0.f, 0.f};
    for (int e = 0; e < 16; ++e) {
        float pe = scores[e];
        float bb[16];
        #pragma unroll
        for (int r = 0; r < 16; ++r) bb[r] = pe * Bm[(size_t)((e << 4) + r) * 1024 + D];
        #pragma unroll
        for (int j = 0; j < 4; ++j) {
            int d = tx + j * 256;
            const float4* ap = (const float4*)(A + (((size_t)e * 1024 + d) << 4));
            float4 a0 = ap[0], a1 = ap[1], a2 = ap[2], a3 = ap[3];
            acc[j] += a0.x*bb[0]  + a0.y*bb[1]  + a0.z*bb[2]  + a0.w*bb[3]
                    + a1.x*bb[4]  + a1.y*bb[5]  + a1.z*bb[6]  + a1.w*bb[7]
                    + a2.x*bb[8]  + a2.y*bb[9]  + a2.z*bb[10] + a2.w*bb[11]
                    + a3.x*bb[12] + a3.y*bb[13] + a3.z*bb[14] + a3.w*bb[15];
        }
    }
    size_t rowbase = (size_t)(1024 + D) * 1024;
    #pragma unroll
    for (int j = 0; j < 4; ++j) wcat[rowbase + tx + j * 256] = f2bf(acc[j]);
}

// ---------- kernel 4: 256x256-tile free-run GEMM, 16x16x32 MFMA ----------
// out2[t][n] = sum_k xb[t][k] * wcat[n][k];  M=32768, N=2048, K=1024.
// BM=BN=256, BK=64, 8 waves (2Mx4N), 128KiB LDS dbuf.
// R6's conflict-free 16x16 read pattern + swizzled coalesced staging,
// R7's free-run schedule: ALL stages -> next-tile buffer (no intra-tile WAR)
// => ONE barrier per K-tile; counted lgkmcnt(4/8/4/0) pipelines 24 ds_reads
// under 64 MFMAs; vmcnt(0) only at tile end.
__global__ __launch_bounds__(512, 2) void gemm_zmf(const unsigned short* __restrict__ xb,
                                                   const unsigned short* __restrict__ wcat,
                                                   const float* __restrict__ bias,
                                                   float* __restrict__ zout) {
    extern __shared__ char lds[];
    const int tid = threadIdx.x;
    const int l = tid & 63;
    const int w = tid >> 6;
    const int wr = w >> 2;        // 0..1
    const int wc = w & 3;         // 0..3

    const int bid = blockIdx.x;
    const int swz = (bid & 7) * 128 + (bid >> 3);
    const int brow = (swz >> 3) * 256;    // 128 M-tiles
    const int bcol = (swz & 7) * 256;     // 8 N-tiles

    // conflict-free 16x16 fragment addressing (R5/R6-proven)
    const unsigned rA128 = (unsigned)((wr * 64 + (l & 15)) * 128);
    const unsigned rB128 = 32768u + (unsigned)((wc * 64 + (l & 15)) * 128);
    const unsigned pck0 = (((l >> 4)) ^ (l & 7)) * 16u;        // ks0 chunk byte
    const unsigned pck1 = ((4 + (l >> 4)) ^ (l & 7)) * 16u;    // ks1 chunk byte

    // staging: thread ti covers row h*128 + ti/8 (+64), phys chunk ti%8,
    // source logical chunk = (ti%8) ^ (row&7)
    const unsigned strow = (unsigned)(tid >> 3);
    const unsigned stchunk = (unsigned)((tid & 7) ^ (strow & 7));
    const unsigned stlds = (unsigned)(tid * 16);

    f32x4 acc[8][4] = {};

#define STAGE(mat, baserow, T, h, bofs) do {                                        \
        int T_ = (T); int Ts_ = T_ > 15 ? 15 : T_;                                  \
        unsigned db_ = (unsigned)((T_ & 1) * 65536) + (bofs) + (h) * 16384u;        \
        const unsigned short* g_ = (mat) + (size_t)((baserow) + (h) * 128 + strow) * 1024 \
                                   + Ts_ * 64 + stchunk * 8;                        \
        gload_lds16(g_,           lds + db_ + stlds);                               \
        gload_lds16(g_ + 64*1024, lds + db_ + 8192 + stlds);                        \
    } while (0)

#define LGKM_SB(N) do {                                                             \
        asm volatile("s_waitcnt lgkmcnt(" #N ")" ::: "memory");                     \
        __builtin_amdgcn_sched_barrier(0);                                          \
    } while (0)

#define RD_A4(dst, bufo, MBASE, PCK) do {                                           \
        dst[0] = ldsrd((bufo) + rA128 + ((MBASE + 0) & 3) * 2048 + ((MBASE + 0) >> 2) * 16384 + (PCK)); \
        dst[1] = ldsrd((bufo) + rA128 + ((MBASE + 1) & 3) * 2048 + ((MBASE + 1) >> 2) * 16384 + (PCK)); \
        dst[2] = ldsrd((bufo) + rA128 + ((MBASE + 2) & 3) * 2048 + ((MBASE + 2) >> 2) * 16384 + (PCK)); \
        dst[3] = ldsrd((bufo) + rA128 + ((MBASE + 3) & 3) * 2048 + ((MBASE + 3) >> 2) * 16384 + (PCK)); \
    } while (0)

#define RD_B4(dst, bufo, PCK) do {                                                  \
        dst[0] = ldsrd((bufo) + rB128 + 0 * 2048 + (PCK));                          \
        dst[1] = ldsrd((bufo) + rB128 + 1 * 2048 + (PCK));                          \
        dst[2] = ldsrd((bufo) + rB128 + 2 * 2048 + (PCK));                          \
        dst[3] = ldsrd((bufo) + rB128 + 3 * 2048 + (PCK));                          \
    } while (0)

#define MFMA16(ABASE, AFR, BFR) do {                                                \
        __builtin_amdgcn_s_setprio(1);                                              \
        _Pragma("unroll")                                                           \
        for (int nf = 0; nf < 4; ++nf) {                                            \
            acc[ABASE + 0][nf] = __builtin_amdgcn_mfma_f32_16x16x32_bf16(AFR[0], BFR[nf], acc[ABASE + 0][nf], 0, 0, 0); \
            acc[ABASE + 1][nf] = __builtin_amdgcn_mfma_f32_16x16x32_bf16(AFR[1], BFR[nf], acc[ABASE + 1][nf], 0, 0, 0); \
            acc[ABASE + 2][nf] = __builtin_amdgcn_mfma_f32_16x16x32_bf16(AFR[2], BFR[nf], acc[ABASE + 2][nf], 0, 0, 0); \
            acc[ABASE + 3][nf] = __builtin_amdgcn_mfma_f32_16x16x32_bf16(AFR[3], BFR[nf], acc[ABASE + 3][nf], 0, 0, 0); \
        }                                                                           \
        __builtin_amdgcn_s_setprio(0);                                              \
    } while (0)

    // ---- prologue: tile 0 fully staged -> buf0 ----
    STAGE(xb,   brow, 0, 0, 0u);
    STAGE(wcat, bcol, 0, 0, 32768u);
    STAGE(xb,   brow, 0, 1, 0u);
    STAGE(wcat, bcol, 0, 1, 32768u);
    asm volatile("s_waitcnt vmcnt(0)" ::: "memory");
    __builtin_amdgcn_s_barrier();

    for (int t = 0; t < 16; ++t) {
        const unsigned bufo = (unsigned)((t & 1) * 65536);
        bf16x8 aL[4], aH[4], aL2[4], aH2[4], b0[4], b1[4];

        RD_A4(aL, bufo, 0, pck0);                   // 4
        RD_B4(b0, bufo, pck0);                      // 8
        STAGE(xb, brow, t + 1, 0, 0u);              // A-h0(t+1) -> nbuf
        RD_A4(aH, bufo, 4, pck0);                   // 12
        LGKM_SB(4);                                 // aL,b0 landed
        MFMA16(0, aL, b0);

        STAGE(wcat, bcol, t + 1, 0, 32768u);        // B-h0(t+1) -> nbuf
        RD_A4(aL2, bufo, 0, pck1);                  // 8
        RD_B4(b1, bufo, pck1);                      // 12
        LGKM_SB(8);                                 // aH landed
        MFMA16(4, aH, b0);

        STAGE(xb, brow, t + 1, 1, 0u);              // A-h1(t+1) -> nbuf
        RD_A4(aH2, bufo, 4, pck1);                  // 12
        LGKM_SB(4);                                 // aL2,b1 landed
        MFMA16(0, aL2, b1);

        STAGE(wcat, bcol, t + 1, 1, 32768u);        // B-h1(t+1) -> nbuf
        LGKM_SB(0);                                 // aH2 landed
        MFMA16(4, aH2, b1);

        // next tile reads nbuf immediately: drain the 8 stage loads, sync
        asm volatile("s_waitcnt vmcnt(0)" ::: "memory");
        __builtin_amdgcn_s_barrier();
    }

    // ---- C-write: scatter acc -> LDS [256][256] bf16, then coalesced out ----
    unsigned short* tlds = (unsigned short*)lds;
    const bool is_z = (bcol < 1024);
    {
        const int crow = wr * 64 + (l >> 4) * 4;
        const int ccol = wc * 64 + (l & 15);
        #pragma unroll
        for (int nf = 0; nf < 4; ++nf) {
            int col = ccol + nf * 16;
            float bb = is_z ? bias[bcol + col] : 0.f;
            #pragma unroll
            for (int mf = 0; mf < 8; ++mf) {
                int row = crow + (mf & 3) * 16 + (mf >> 2) * 128;
                f32x4 v = acc[mf][nf];
                #pragma unroll
                for (int j = 0; j < 4; ++j)
                    tlds[(row + j) * 256 + col] = f2bf(v[j] + bb);
            }
        }
    }
    __syncthreads();
    {
        // d_out as packed bf16: row r = [1024 z | 1024 m] (u16 units, 2048/row)
        unsigned short* og = (unsigned short*)zout;
        const int rr = tid >> 5;           // 0..15
        const int c16 = (tid & 31) * 8;    // u16 col within 256
        #pragma unroll
        for (int p = 0; p < 16; ++p) {
            int row = p * 16 + rr;
            u16x8 v = *(const u16x8*)&tlds[row * 256 + c16];
            *(u16x8*)&og[(size_t)(brow + row) * 2048 + bcol + c16] = v;
        }
    }
#undef STAGE
#undef LGKM_SB
#undef RD_A4
#undef RD_B4
#undef MFMA16
}

// ---------- kernel 5: in-place norm-clamp epilogue ----------
// d_out row r arrives as packed bf16 [1024 z | 1024 m]; leaves as 1024 fp32.
__global__ __launch_bounds__(256) void epilogue_ip(float* out, const int* __restrict__ lidx) {
    int row = blockIdx.x;            // 32768
    int tx = threadIdx.x;            // 256
    const unsigned short* io = (const unsigned short*)out;
    size_t base = (size_t)row * 2048;

    ushort4 zv = *(const ushort4*)&io[base + tx * 4];
    ushort4 mv = *(const ushort4*)&io[base + 1024 + tx * 4];
    float z0 = bf2f(zv.x), z1 = bf2f(zv.y), z2 = bf2f(zv.z), z3 = bf2f(zv.w);
    float m0 = bf2f(mv.x), m1 = bf2f(mv.y), m2 = bf2f(mv.z), m3 = bf2f(mv.w);

    float sz = z0 * z0 + z1 * z1 + z2 * z2 + z3 * z3;
    float sm = m0 * m0 + m1 * m1 + m2 * m2 + m3 * m3;

    #pragma unroll
    for (int off = 32; off > 0; off >>= 1) {
        sz += __shfl_xor(sz, off);
        sm += __shfl_xor(sm, off);
    }
    __shared__ float red[8];
    int wv = tx >> 6;
    if ((tx & 63) == 0) { red[wv * 2] = sz; red[wv * 2 + 1] = sm; }
    __syncthreads();   // also orders: ALL row reads complete before ANY writes
    sz = red[0] + red[2] + red[4] + red[6];
    sm = red[1] + red[3] + red[5] + red[7];

    float gamma = fminf(0.5f * sqrtf(sz) / (sqrtf(sm) + 1e-6f), 1.0f);
    if (lidx[0] < 0) gamma = 0.f;

    float4 o;
    o.x = z0 + gamma * m0; o.y = z1 + gamma * m1;
    o.z = z2 + gamma * m2; o.w = z3 + gamma * m3;
    *(float4*)&out[(size_t)row * 1024 + tx * 4] = o;
}

// ---------- launcher ----------
extern "C" void kernel_launch(void* const* d_in, const int* in_sizes, int n_in,
                              void* d_out, int out_size, void* d_ws, size_t ws_size,
                              hipStream_t stream) {
    const float* x  = (const float*)d_in[0];
    const float* W  = (const float*)d_in[1];
    const float* b  = (const float*)d_in[2];
    const float* A  = (const float*)d_in[3];
    const float* Bm = (const float*)d_in[4];
    const float* sc = (const float*)d_in[5];
    const int* lidx = (const int*)d_in[6];
    float* out = (float*)d_out;

    // ws layout (bytes): xb 64MB | wcat 4MB   (68MB total)
    unsigned short* xb   = (unsigned short*)d_ws;
    unsigned short* wcat = (unsigned short*)((char*)d_ws + 67108864);

    hipFuncSetAttribute((const void*)gemm_zmf,
                        hipFuncAttributeMaxDynamicSharedMemorySize, 131072);

    cast_x<<<2048, 256, 0, stream>>>(x, xb, 33554432 / 4);
    cast_w<<<1024, 256, 0, stream>>>(W, wcat);
    build_m<<<1024, 256, 0, stream>>>(A, Bm, sc, wcat);
    gemm_zmf<<<1024, 512, 131072, stream>>>(xb, wcat, b, out);
    epilogue_ip<<<32768, 256, 0, stream>>>(out, lidx);
}